// Round 5
// baseline (2302.862 us; speedup 1.0000x reference)
//
#include <hip/hip_runtime.h>

// StackedFlow v5: STATIC LDS to unlock the VGPR budget.
// r4: VGPR_Count still 128, WRITE_SIZE 91MB (~82MB spill stores). Hypothesis: with
// extern __shared__ (dynamic LDS) the AMDGPU backend's occupancy model assumes LDS=0,
// targets 4 waves/EU, and caps VGPRs at 128 regardless of launch_bounds/waves_per_eu
// hints -> persistent spills. Fix: static __shared__ char smem[158976] makes the 155KB
// group segment compile-time visible -> occupancy provably 2 waves/EU -> 256-VGPR budget.
// Everything else identical to v4 (clean A/B on the spill theory).

#define LNUM   4
#define NSTEP  8
#define EPSV   1e-3f

typedef __attribute__((ext_vector_type(8))) short  short8;
typedef __attribute__((ext_vector_type(4))) float  floatx4;

#define MF(a, b, c) __builtin_amdgcn_mfma_f32_16x16x32_bf16((a), (b), (c), 0, 0, 0)

// d_ws layout (bf16 element offsets), per-GEMM fragment arrays [layer][nt*KS+ks][lane][8]
#define OW0_OFF 0        // ode W0 rows 1..64  (64 x 256)
#define OW1_OFF 65536    // ode W1            (256 x 256)
#define OW2_OFF 327680   // ode W2            (256 x 64)
#define NW0_OFF 393216   // nvp W0            (32 x 256)
#define NW1_OFF 425984   // nvp W1            (256 x 256)
#define NW2_OFF 688128   // nvp W2            (256 x 64)
#define WS_ELEMS 753664

// LDS byte offsets
#define H1_OFF   0        // 64K bf16 [128][256] RS=512 swz((m&7)<<4)
#define YS_OFF   65536    // 32K fp32 [128][64]  RS=256 swz((m&7)<<4)
#define YIN_OFF  98304    // 16K bf16 [128][64]  RS=128 swz((m&7)<<4)   (x0 in NVP phase)
#define SHF_OFF  114688   // 8K  bf16 [128][32]  RS=64  swz((m&3)<<4)
#define W2B_OFF  122880   // 32K short8[2048] W2 fragments (NVP then ODE, staged per phase)
#define PARS_OFF 155648   // 3328B: b0 | b1(+256) | b2(+512) | w0row0(+576)
#define LDS_SIZE 158976

__device__ __forceinline__ unsigned short f2bfu(float f) {
  unsigned int u = __float_as_uint(f);
  return (unsigned short)((u + 0x7FFFu + ((u >> 16) & 1u)) >> 16);  // RNE
}

__device__ __forceinline__ unsigned long long pack4bf(float a, float b, float c, float d) {
  return (unsigned long long)f2bfu(a)
       | ((unsigned long long)f2bfu(b) << 16)
       | ((unsigned long long)f2bfu(c) << 32)
       | ((unsigned long long)f2bfu(d) << 48);
}

__device__ __forceinline__ float bfu2f(unsigned short u) {
  return __uint_as_float((unsigned int)u << 16);
}

__device__ __forceinline__ float tanh_fast(float x) {
  float e = __expf(2.0f * x);
  return 1.0f - 2.0f * __builtin_amdgcn_rcpf(e + 1.0f);
}

// ---------------- weight prep: fp32 [K][N] -> bf16 A-fragment order ----------------
__global__ void prep_kernel(const float* __restrict__ odeW0, const float* __restrict__ odeW1,
                            const float* __restrict__ odeW2, const float* __restrict__ nvpW0,
                            const float* __restrict__ nvpW1, const float* __restrict__ nvpW2,
                            unsigned short* __restrict__ ws) {
  int idx = blockIdx.x * blockDim.x + threadIdx.x;
  if (idx >= WS_ELEMS) return;
  const float* W; int base, K, N, lstride, skip;
  int f = idx;
  if (f < OW1_OFF)      { W = odeW0; base = OW0_OFF; K = 64;  N = 256; lstride = 16640; skip = 1; f -= OW0_OFF; }
  else if (f < OW2_OFF) { W = odeW1; base = OW1_OFF; K = 256; N = 256; lstride = 65536; skip = 0; f -= OW1_OFF; }
  else if (f < NW0_OFF) { W = odeW2; base = OW2_OFF; K = 256; N = 64;  lstride = 16384; skip = 0; f -= OW2_OFF; }
  else if (f < NW1_OFF) { W = nvpW0; base = NW0_OFF; K = 32;  N = 256; lstride = 8192;  skip = 0; f -= NW0_OFF; }
  else if (f < NW2_OFF) { W = nvpW1; base = NW1_OFF; K = 256; N = 256; lstride = 65536; skip = 0; f -= NW1_OFF; }
  else                  { W = nvpW2; base = NW2_OFF; K = 256; N = 64;  lstride = 16384; skip = 0; f -= NW2_OFF; }
  int per   = K * N;
  int layer = f / per;
  int e     = f - layer * per;
  int j  = e & 7;
  int l  = (e >> 3) & 63;
  int t  = e >> 9;                 // nt*KS + ks
  int KS = K >> 5; if (KS < 1) KS = 1;
  int ks = t % KS;
  int nt = t / KS;
  int n = nt * 16 + (l & 15);
  int k = ks * 32 + ((l >> 4) << 3) + j;
  ws[base + layer * per + e] = f2bfu(W[layer * lstride + (k + skip) * N + n]);
}

// store 4 consecutive n of batch-row m as bf16 into h1 [m][256] swizzled (RS=512B)
__device__ __forceinline__ void st_h(char* dst, int m, int n0, float a, float b, float c, float d) {
  int off = (m * 512 + n0 * 2) ^ ((m & 7) << 4);
  *reinterpret_cast<unsigned long long*>(dst + off) = pack4bf(a, b, c, d);
}

__device__ __forceinline__ void bn_apply(float y[16], const float* __restrict__ mptr,
                                         const float* __restrict__ vptr, const float* __restrict__ gptr,
                                         const float* __restrict__ bptr, int d0) {
  floatx4 mm = *reinterpret_cast<const floatx4*>(mptr + d0);
  floatx4 vv = *reinterpret_cast<const floatx4*>(vptr + d0);
  floatx4 gg = *reinterpret_cast<const floatx4*>(gptr + d0);
  floatx4 be = *reinterpret_cast<const floatx4*>(bptr + d0);
  float sc[4];
  #pragma unroll
  for (int p = 0; p < 4; ++p) sc[p] = sqrtf(vv[p] + EPSV) / gg[p];
  #pragma unroll
  for (int mt = 0; mt < 4; ++mt)
    #pragma unroll
    for (int p = 0; p < 4; ++p)
      y[mt * 4 + p] = (y[mt * 4 + p] - be[p]) * sc[p] + mm[p];
}

// ---------------- fused flow kernel ----------------
__global__ void
__launch_bounds__(512)
__attribute__((amdgpu_waves_per_eu(2, 2)))
flow_kernel(const float* __restrict__ xin,
            const float* __restrict__ nvp_b0, const float* __restrict__ nvp_b1,
            const float* __restrict__ nvp_b2,
            const float* __restrict__ odeW0_full,
            const float* __restrict__ ode_b0, const float* __restrict__ ode_b1,
            const float* __restrict__ ode_b2,
            const float* __restrict__ bn1m, const float* __restrict__ bn1v,
            const float* __restrict__ bn1g, const float* __restrict__ bn1b,
            const float* __restrict__ bn2m, const float* __restrict__ bn2v,
            const float* __restrict__ bn2g, const float* __restrict__ bn2b,
            const unsigned short* __restrict__ ws,
            float* __restrict__ out) {
  __shared__ __align__(16) char smem[LDS_SIZE];   // STATIC: occupancy-visible to the allocator
  char*  h1   = smem + H1_OFF;
  char*  ysb  = smem + YS_OFF;
  char*  yinb = smem + YIN_OFF;
  char*  shfb = smem + SHF_OFF;
  short8* w2f = reinterpret_cast<short8*>(smem + W2B_OFF);
  float* pars = reinterpret_cast<float*>(smem + PARS_OFF);

  const int tid  = threadIdx.x;
  const int lane = tid & 63;
  const int w    = tid >> 6;
  const int l15  = lane & 15;
  const int g    = lane >> 4;
  const int wn   = w & 3;
  const int wm   = w >> 2;
  const int m0   = blockIdx.x * 128 + wm * 64;
  const int d0   = wn * 16 + g * 4;
  const float dtv = 1.0f / NSTEP;

  float y[16];  // y[mt*4+p] at row (m0 + mt*16 + l15), dim (d0 + p)
  #pragma unroll
  for (int mt = 0; mt < 4; ++mt) {
    floatx4 v = *reinterpret_cast<const floatx4*>(xin + (m0 + mt * 16 + l15) * 64 + d0);
    y[mt * 4 + 0] = v[0]; y[mt * 4 + 1] = v[1]; y[mt * 4 + 2] = v[2]; y[mt * 4 + 3] = v[3];
  }

  short8 aw0[2][2];   // G1 A-frags (wave's n-slice [32w, 32w+32))
  short8 aw1[2][8];   // G2 A-frags

  for (int l = 0; l < LNUM; ++l) {
    // ---- NVP weight slices into registers ----
    {
      const short8* p0 = reinterpret_cast<const short8*>(ws + NW0_OFF + l * 8192);
      const short8* p1 = reinterpret_cast<const short8*>(ws + NW1_OFF + l * 65536);
      #pragma unroll
      for (int nt = 0; nt < 2; ++nt) aw0[nt][0] = p0[(w * 2 + nt) * 64 + lane];
      #pragma unroll
      for (int nt = 0; nt < 2; ++nt)
        #pragma unroll
        for (int ks = 0; ks < 8; ++ks) aw1[nt][ks] = p1[((w * 2 + nt) * 8 + ks) * 64 + lane];
    }

    // ================= perm + RealNVP =================
    __syncthreads();                       // prev-layer LDS readers done
    #pragma unroll
    for (int mt = 0; mt < 4; ++mt) {       // stash y fp32 into ys
      int m = wm * 64 + mt * 16 + l15;
      floatx4 v = {y[mt * 4 + 0], y[mt * 4 + 1], y[mt * 4 + 2], y[mt * 4 + 3]};
      int off = (m * 256 + d0 * 4) ^ ((m & 7) << 4);
      *reinterpret_cast<floatx4*>(ysb + off) = v;
    }
    if (wn >= 2) {                         // x0 (= y dims 32..63) bf16 into yin region
      #pragma unroll
      for (int mt = 0; mt < 4; ++mt) {
        int m = wm * 64 + mt * 16 + l15;
        int off = (m * 128 + (d0 - 32) * 2) ^ ((m & 7) << 4);
        *reinterpret_cast<unsigned long long*>(yinb + off) =
            pack4bf(y[mt * 4 + 0], y[mt * 4 + 1], y[mt * 4 + 2], y[mt * 4 + 3]);
      }
    }
    for (int i = tid; i < 576; i += 512) { // NVP biases
      float v;
      if (i < 256)      v = nvp_b0[l * 256 + i];
      else if (i < 512) v = nvp_b1[l * 256 + i - 256];
      else              v = nvp_b2[l * 64 + i - 512];
      pars[i] = v;
    }
    {                                      // NVP W2 fragments -> LDS
      const short8* src = reinterpret_cast<const short8*>(ws + NW2_OFF + l * 16384);
      for (int i = tid; i < 2048; i += 512) w2f[i] = src[i];
    }
    __syncthreads();

    // ---- NVP G1: h1 = relu(x0 @ W0n + b0n) ----
    #pragma unroll
    for (int mh = 0; mh < 2; ++mh) {
      floatx4 acc[2][4];
      #pragma unroll
      for (int nt = 0; nt < 2; ++nt)
        #pragma unroll
        for (int mt = 0; mt < 4; ++mt) acc[nt][mt] = floatx4{0.f, 0.f, 0.f, 0.f};
      short8 B[4];
      #pragma unroll
      for (int mt = 0; mt < 4; ++mt) {
        int m = mh * 64 + mt * 16 + l15;
        int off = (m * 128 + (g * 8) * 2) ^ ((m & 7) << 4);
        B[mt] = *reinterpret_cast<const short8*>(yinb + off);
      }
      #pragma unroll
      for (int nt = 0; nt < 2; ++nt)
        #pragma unroll
        for (int mt = 0; mt < 4; ++mt) acc[nt][mt] = MF(aw0[nt][0], B[mt], acc[nt][mt]);
      #pragma unroll
      for (int nt = 0; nt < 2; ++nt) {
        int nb = w * 32 + nt * 16 + g * 4;
        floatx4 bb = *reinterpret_cast<const floatx4*>(pars + nb);
        #pragma unroll
        for (int mt = 0; mt < 4; ++mt) {
          int m = mh * 64 + mt * 16 + l15;
          st_h(h1, m, nb,
               fmaxf(acc[nt][mt][0] + bb[0], 0.f), fmaxf(acc[nt][mt][1] + bb[1], 0.f),
               fmaxf(acc[nt][mt][2] + bb[2], 0.f), fmaxf(acc[nt][mt][3] + bb[3], 0.f));
        }
      }
    }
    __syncthreads();

    // ---- NVP G2: relu(h1 @ W1n + b1n), in-place h1 ----
    #pragma unroll
    for (int mh = 0; mh < 2; ++mh) {
      floatx4 acc[2][4];
      #pragma unroll
      for (int nt = 0; nt < 2; ++nt)
        #pragma unroll
        for (int mt = 0; mt < 4; ++mt) acc[nt][mt] = floatx4{0.f, 0.f, 0.f, 0.f};
      #pragma unroll
      for (int ks = 0; ks < 8; ++ks) {
        short8 B[4];
        #pragma unroll
        for (int mt = 0; mt < 4; ++mt) {
          int m = mh * 64 + mt * 16 + l15;
          int off = (m * 512 + (ks * 32 + g * 8) * 2) ^ ((m & 7) << 4);
          B[mt] = *reinterpret_cast<const short8*>(h1 + off);
        }
        #pragma unroll
        for (int nt = 0; nt < 2; ++nt)
          #pragma unroll
          for (int mt = 0; mt < 4; ++mt) acc[nt][mt] = MF(aw1[nt][ks], B[mt], acc[nt][mt]);
      }
      __syncthreads();
      #pragma unroll
      for (int nt = 0; nt < 2; ++nt) {
        int nb = w * 32 + nt * 16 + g * 4;
        floatx4 bb = *reinterpret_cast<const floatx4*>(pars + 256 + nb);
        #pragma unroll
        for (int mt = 0; mt < 4; ++mt) {
          int m = mh * 64 + mt * 16 + l15;
          st_h(h1, m, nb,
               fmaxf(acc[nt][mt][0] + bb[0], 0.f), fmaxf(acc[nt][mt][1] + bb[1], 0.f),
               fmaxf(acc[nt][mt][2] + bb[2], 0.f), fmaxf(acc[nt][mt][3] + bb[3], 0.f));
        }
      }
    }
    __syncthreads();

    // ---- NVP G3: [shift|logscale] = h2 @ W2n + b2n  (A from LDS w2f) ----
    floatx4 a3[4];
    #pragma unroll
    for (int mt = 0; mt < 4; ++mt) a3[mt] = floatx4{0.f, 0.f, 0.f, 0.f};
    #pragma unroll
    for (int ks = 0; ks < 8; ++ks) {
      short8 A = w2f[(wn * 8 + ks) * 64 + lane];
      #pragma unroll
      for (int mt = 0; mt < 4; ++mt) {
        int m = wm * 64 + mt * 16 + l15;
        int off = (m * 512 + (ks * 32 + g * 8) * 2) ^ ((m & 7) << 4);
        short8 B = *reinterpret_cast<const short8*>(h1 + off);
        a3[mt] = MF(A, B, a3[mt]);
      }
    }
    {
      floatx4 b2v = *reinterpret_cast<const floatx4*>(pars + 512 + d0);
      #pragma unroll
      for (int mt = 0; mt < 4; ++mt)
        #pragma unroll
        for (int p = 0; p < 4; ++p) a3[mt][p] += b2v[p];
    }

    // ---- ODE weight slices into registers ----
    {
      const short8* p0 = reinterpret_cast<const short8*>(ws + OW0_OFF + l * 16384);
      const short8* p1 = reinterpret_cast<const short8*>(ws + OW1_OFF + l * 65536);
      #pragma unroll
      for (int nt = 0; nt < 2; ++nt)
        #pragma unroll
        for (int ks = 0; ks < 2; ++ks) aw0[nt][ks] = p0[((w * 2 + nt) * 2 + ks) * 64 + lane];
      #pragma unroll
      for (int nt = 0; nt < 2; ++nt)
        #pragma unroll
        for (int ks = 0; ks < 8; ++ks) aw1[nt][ks] = p1[((w * 2 + nt) * 8 + ks) * 64 + lane];
    }

    if (wn < 2) {                          // stash shift (dims 0..31) bf16
      #pragma unroll
      for (int mt = 0; mt < 4; ++mt) {
        int m = wm * 64 + mt * 16 + l15;
        int off = (m * 64 + d0 * 2) ^ ((m & 3) << 4);
        *reinterpret_cast<unsigned long long*>(shfb + off) =
            pack4bf(a3[mt][0], a3[mt][1], a3[mt][2], a3[mt][3]);
      }
    }
    __syncthreads();                       // G3 w2f/h1 reads + shift writes done
    if (wn < 2) {                          // new y[d<32] = old y[d+32]
      #pragma unroll
      for (int mt = 0; mt < 4; ++mt) {
        int m = wm * 64 + mt * 16 + l15;
        int off = (m * 256 + (d0 + 32) * 4) ^ ((m & 7) << 4);
        floatx4 v = *reinterpret_cast<const floatx4*>(ysb + off);
        y[mt * 4 + 0] = v[0]; y[mt * 4 + 1] = v[1]; y[mt * 4 + 2] = v[2]; y[mt * 4 + 3] = v[3];
      }
    } else {                               // new y[32+j] = x1[j]*exp(ls[j]) + shift[j]
      #pragma unroll
      for (int mt = 0; mt < 4; ++mt) {
        int m = wm * 64 + mt * 16 + l15;
        int offx = (m * 256 + (d0 - 32) * 4) ^ ((m & 7) << 4);
        floatx4 x1 = *reinterpret_cast<const floatx4*>(ysb + offx);
        int offs = (m * 64 + (d0 - 32) * 2) ^ ((m & 3) << 4);
        unsigned long long u = *reinterpret_cast<const unsigned long long*>(shfb + offs);
        float sh0 = bfu2f((unsigned short)(u));
        float sh1 = bfu2f((unsigned short)(u >> 16));
        float sh2 = bfu2f((unsigned short)(u >> 32));
        float sh3 = bfu2f((unsigned short)(u >> 48));
        y[mt * 4 + 0] = x1[0] * __expf(a3[mt][0]) + sh0;
        y[mt * 4 + 1] = x1[1] * __expf(a3[mt][1]) + sh1;
        y[mt * 4 + 2] = x1[2] * __expf(a3[mt][2]) + sh2;
        y[mt * 4 + 3] = x1[3] * __expf(a3[mt][3]) + sh3;
      }
    }
    bn_apply(y, bn1m + l * 64, bn1v + l * 64, bn1g + l * 64, bn1b + l * 64, d0);

    for (int i = tid; i < 832; i += 512) { // ODE biases + t-row
      float v;
      if (i < 256)      v = ode_b0[l * 256 + i];
      else if (i < 512) v = ode_b1[l * 256 + i - 256];
      else if (i < 576) v = ode_b2[l * 64 + i - 512];
      else              v = odeW0_full[l * 16640 + i - 576];
      pars[i] = v;
    }
    {                                      // ODE W2 fragments -> LDS
      const short8* src = reinterpret_cast<const short8*>(ws + OW2_OFF + l * 16384);
      for (int i = tid; i < 2048; i += 512) w2f[i] = src[i];
    }

    // ================= FFJORD: 8 RK4 steps =================
    float ka[16], kc[16];
    for (int s = 0; s < NSTEP; ++s) {
      float t0 = (float)s * dtv;
      for (int stg = 0; stg < 4; ++stg) {
        float cadd = (stg == 0) ? 0.0f : ((stg == 3) ? dtv : 0.5f * dtv);
        float tcur = t0 + cadd;
        #pragma unroll
        for (int mt = 0; mt < 4; ++mt) {   // yin bf16 [128][64] swz RS=128
          int m = wm * 64 + mt * 16 + l15;
          float v0, v1, v2, v3;
          if (stg == 0) {
            v0 = y[mt * 4 + 0]; v1 = y[mt * 4 + 1]; v2 = y[mt * 4 + 2]; v3 = y[mt * 4 + 3];
          } else {
            v0 = fmaf(cadd, kc[mt * 4 + 0], y[mt * 4 + 0]);
            v1 = fmaf(cadd, kc[mt * 4 + 1], y[mt * 4 + 1]);
            v2 = fmaf(cadd, kc[mt * 4 + 2], y[mt * 4 + 2]);
            v3 = fmaf(cadd, kc[mt * 4 + 3], y[mt * 4 + 3]);
          }
          int off = (m * 128 + d0 * 2) ^ ((m & 7) << 4);
          *reinterpret_cast<unsigned long long*>(yinb + off) = pack4bf(v0, v1, v2, v3);
        }
        __syncthreads();                   // yin ready; prev G3 h1-reads done

        // G1: h1 = tanh(yin @ W0o + b0o + tcur*w0row0)
        #pragma unroll
        for (int mh = 0; mh < 2; ++mh) {
          floatx4 acc[2][4];
          #pragma unroll
          for (int nt = 0; nt < 2; ++nt)
            #pragma unroll
            for (int mt = 0; mt < 4; ++mt) acc[nt][mt] = floatx4{0.f, 0.f, 0.f, 0.f};
          #pragma unroll
          for (int ks = 0; ks < 2; ++ks) {
            short8 B[4];
            #pragma unroll
            for (int mt = 0; mt < 4; ++mt) {
              int m = mh * 64 + mt * 16 + l15;
              int off = (m * 128 + (ks * 32 + g * 8) * 2) ^ ((m & 7) << 4);
              B[mt] = *reinterpret_cast<const short8*>(yinb + off);
            }
            #pragma unroll
            for (int nt = 0; nt < 2; ++nt)
              #pragma unroll
              for (int mt = 0; mt < 4; ++mt) acc[nt][mt] = MF(aw0[nt][ks], B[mt], acc[nt][mt]);
          }
          #pragma unroll
          for (int nt = 0; nt < 2; ++nt) {
            int nb = w * 32 + nt * 16 + g * 4;
            floatx4 bb = *reinterpret_cast<const floatx4*>(pars + nb);
            floatx4 w0 = *reinterpret_cast<const floatx4*>(pars + 576 + nb);
            float c0 = bb[0] + tcur * w0[0], c1 = bb[1] + tcur * w0[1];
            float c2 = bb[2] + tcur * w0[2], c3 = bb[3] + tcur * w0[3];
            #pragma unroll
            for (int mt = 0; mt < 4; ++mt) {
              int m = mh * 64 + mt * 16 + l15;
              st_h(h1, m, nb,
                   tanh_fast(acc[nt][mt][0] + c0), tanh_fast(acc[nt][mt][1] + c1),
                   tanh_fast(acc[nt][mt][2] + c2), tanh_fast(acc[nt][mt][3] + c3));
            }
          }
        }
        __syncthreads();

        // G2: h2 = tanh(h1 @ W1o + b1o), in-place h1
        #pragma unroll
        for (int mh = 0; mh < 2; ++mh) {
          floatx4 acc[2][4];
          #pragma unroll
          for (int nt = 0; nt < 2; ++nt)
            #pragma unroll
            for (int mt = 0; mt < 4; ++mt) acc[nt][mt] = floatx4{0.f, 0.f, 0.f, 0.f};
          #pragma unroll
          for (int ks = 0; ks < 8; ++ks) {
            short8 B[4];
            #pragma unroll
            for (int mt = 0; mt < 4; ++mt) {
              int m = mh * 64 + mt * 16 + l15;
              int off = (m * 512 + (ks * 32 + g * 8) * 2) ^ ((m & 7) << 4);
              B[mt] = *reinterpret_cast<const short8*>(h1 + off);
            }
            #pragma unroll
            for (int nt = 0; nt < 2; ++nt)
              #pragma unroll
              for (int mt = 0; mt < 4; ++mt) acc[nt][mt] = MF(aw1[nt][ks], B[mt], acc[nt][mt]);
          }
          __syncthreads();
          #pragma unroll
          for (int nt = 0; nt < 2; ++nt) {
            int nb = w * 32 + nt * 16 + g * 4;
            floatx4 bb = *reinterpret_cast<const floatx4*>(pars + 256 + nb);
            #pragma unroll
            for (int mt = 0; mt < 4; ++mt) {
              int m = mh * 64 + mt * 16 + l15;
              st_h(h1, m, nb,
                   tanh_fast(acc[nt][mt][0] + bb[0]), tanh_fast(acc[nt][mt][1] + bb[1]),
                   tanh_fast(acc[nt][mt][2] + bb[2]), tanh_fast(acc[nt][mt][3] + bb[3]));
            }
          }
        }
        __syncthreads();

        // G3: k = h2 @ W2o + b2o  (A from LDS w2f)
        floatx4 a2[4];
        #pragma unroll
        for (int mt = 0; mt < 4; ++mt) a2[mt] = floatx4{0.f, 0.f, 0.f, 0.f};
        #pragma unroll
        for (int ks = 0; ks < 8; ++ks) {
          short8 A = w2f[(wn * 8 + ks) * 64 + lane];
          #pragma unroll
          for (int mt = 0; mt < 4; ++mt) {
            int m = wm * 64 + mt * 16 + l15;
            int off = (m * 512 + (ks * 32 + g * 8) * 2) ^ ((m & 7) << 4);
            short8 B = *reinterpret_cast<const short8*>(h1 + off);
            a2[mt] = MF(A, B, a2[mt]);
          }
        }
        {
          floatx4 b2v = *reinterpret_cast<const floatx4*>(pars + 512 + d0);
          #pragma unroll
          for (int mt = 0; mt < 4; ++mt)
            #pragma unroll
            for (int p = 0; p < 4; ++p)
              kc[mt * 4 + p] = a2[mt][p] + b2v[p];
        }
        if (stg == 0) {
          #pragma unroll
          for (int i = 0; i < 16; ++i) ka[i] = kc[i];
        } else if (stg == 3) {
          #pragma unroll
          for (int i = 0; i < 16; ++i) ka[i] += kc[i];
        } else {
          #pragma unroll
          for (int i = 0; i < 16; ++i) ka[i] += 2.0f * kc[i];
        }
      }
      #pragma unroll
      for (int i = 0; i < 16; ++i) y[i] += (dtv / 6.0f) * ka[i];
    }

    bn_apply(y, bn2m + l * 64, bn2v + l * 64, bn2g + l * 64, bn2b + l * 64, d0);
  }

  #pragma unroll
  for (int mt = 0; mt < 4; ++mt) {
    floatx4 v = {y[mt * 4 + 0], y[mt * 4 + 1], y[mt * 4 + 2], y[mt * 4 + 3]};
    *reinterpret_cast<floatx4*>(out + (m0 + mt * 16 + l15) * 64 + d0) = v;
  }
}

extern "C" void kernel_launch(void* const* d_in, const int* in_sizes, int n_in,
                              void* d_out, int out_size, void* d_ws, size_t ws_size,
                              hipStream_t stream) {
  const float* x      = (const float*)d_in[0];
  const float* nvpW0  = (const float*)d_in[2];
  const float* nvp_b0 = (const float*)d_in[3];
  const float* nvpW1  = (const float*)d_in[4];
  const float* nvp_b1 = (const float*)d_in[5];
  const float* nvpW2  = (const float*)d_in[6];
  const float* nvp_b2 = (const float*)d_in[7];
  const float* odeW0  = (const float*)d_in[8];
  const float* ode_b0 = (const float*)d_in[9];
  const float* odeW1  = (const float*)d_in[10];
  const float* ode_b1 = (const float*)d_in[11];
  const float* odeW2  = (const float*)d_in[12];
  const float* ode_b2 = (const float*)d_in[13];
  const float* bn1m   = (const float*)d_in[14];
  const float* bn1v   = (const float*)d_in[15];
  const float* bn1g   = (const float*)d_in[16];
  const float* bn1b   = (const float*)d_in[17];
  const float* bn2m   = (const float*)d_in[18];
  const float* bn2v   = (const float*)d_in[19];
  const float* bn2g   = (const float*)d_in[20];
  const float* bn2b   = (const float*)d_in[21];
  unsigned short* ws  = (unsigned short*)d_ws;
  float* out          = (float*)d_out;

  int pblocks = (WS_ELEMS + 255) / 256;
  prep_kernel<<<pblocks, 256, 0, stream>>>(odeW0, odeW1, odeW2, nvpW0, nvpW1, nvpW2, ws);
  flow_kernel<<<256, 512, 0, stream>>>(x, nvp_b0, nvp_b1, nvp_b2, odeW0,
                                       ode_b0, ode_b1, ode_b2,
                                       bn1m, bn1v, bn1g, bn1b,
                                       bn2m, bn2v, bn2g, bn2b,
                                       ws, out);
}